// Round 2
// baseline (105.293 us; speedup 1.0000x reference)
//
#include <hip/hip_runtime.h>

// TiledEquivariantMLP — live-path-only implementation.
// Dead-code analysis of the reference: only the l=0 (scalar) channel affects
// the output. Per atom: h1=silu(x0@W0_0[:, :64]/sqrt(32)); h2=silu(h1@W1_0[:, :64]/8);
// y=h2@Wout/8; summed per (batch, class).  (Gates y0[:,64:256] only multiply
// l>0 irreps, which are dead because the final output reads only b[0].)
//
// Grid: (10 classes, 32 batches). Each block owns out[b, c*128:(c+1)*128]
// exclusively -> no atomics, no output pre-zero, no workspace.

#define NCLS  10
#define NB    32
#define NATOM 512
#define DIN   272

__global__ __launch_bounds__(256) void eqmlp_fused(
    const float* __restrict__ x,       // (32, 512, 272)
    const float* __restrict__ W0,      // (10, 32, 256)  use cols [0,64)
    const float* __restrict__ W1,      // (10, 64, 256)  use cols [0,64)
    const float* __restrict__ Wo,      // (10, 64, 128)
    const int*   __restrict__ mapping, // (32, 512) values 0..10 (10 = unused)
    float*       __restrict__ out)     // (32, 1280)
{
    const int c    = blockIdx.x;
    const int b    = blockIdx.y;
    const int tid  = threadIdx.x;
    const int w    = tid >> 6;   // wave 0..3
    const int lane = tid & 63;

    __shared__ __align__(16) float W0s[32 * 64];    //  8 KB  [m][o]
    __shared__ __align__(16) float W1s[64 * 64];    // 16 KB  [m][o]
    __shared__ __align__(16) float Wos[64 * 128];   // 32 KB  [m][o]
    __shared__ __align__(16) float xbuf [4][32 * 4]; // per-wave, m-major x4 atoms
    __shared__ __align__(16) float h1buf[4][64 * 4]; // per-wave
    __shared__ __align__(16) float hsbuf[4][64];     // per-wave, atom-summed h2
    __shared__ __align__(16) float red[4 * 128];

    // ---- stage live weight slices into LDS (coalesced float4) ----
    {
        const float4* g0 = (const float4*)(W0 + (size_t)c * 32 * 256);
        float4* s = (float4*)W0s;
        for (int i = tid; i < 32 * 64 / 4; i += 256)       // row o-slice [0,64)
            s[i] = g0[(i >> 4) * 64 + (i & 15)];
        const float4* g1 = (const float4*)(W1 + (size_t)c * 64 * 256);
        float4* s1 = (float4*)W1s;
        for (int i = tid; i < 64 * 64 / 4; i += 256)
            s1[i] = g1[(i >> 4) * 64 + (i & 15)];
        const float4* g2 = (const float4*)(Wo + (size_t)c * 64 * 128);
        float4* s2 = (float4*)Wos;
        for (int i = tid; i < 64 * 128 / 4; i += 256)      // contiguous
            s2[i] = g2[i];
    }
    __syncthreads();

    float accA = 0.f, accB = 0.f;   // outputs lane and lane+64

    const int*   map_b = mapping + b * NATOM;
    const float* x_b   = x + (size_t)b * NATOM * DIN;
    const float  sc0   = 0.17677669529663689f;  // 1/sqrt(32)
    const float  sc1   = 0.125f;                // 1/sqrt(64)

    for (int chunk = 0; chunk < 2; ++chunk) {
        const int base = w * 128 + chunk * 64;          // this wave's 64 atoms
        const int mv   = map_b[base + lane];
        unsigned long long mask = __ballot(mv == c);    // wave-uniform

        while (mask) {
            // ---- pop up to 4 matched atom indices (wave-uniform scalars) ----
            int a0 = 0, a1 = 0, a2 = 0, a3 = 0, na = 0;
            {             int p = __builtin_ctzll(mask); mask &= mask - 1; a0 = base + p; na = 1; }
            if (mask)   { int p = __builtin_ctzll(mask); mask &= mask - 1; a1 = base + p; na = 2; }
            if (mask)   { int p = __builtin_ctzll(mask); mask &= mask - 1; a2 = base + p; na = 3; }
            if (mask)   { int p = __builtin_ctzll(mask); mask &= mask - 1; a3 = base + p; na = 4; }

            // ---- load x0 (first 32 feats) for up to 4 atoms, m-major in LDS ----
            {
                const int m  = lane & 31;
                const int jh = lane >> 5;               // 0 or 1
                const int e0 = jh ? a1 : a0;            // j = jh
                const int e1 = jh ? a3 : a2;            // j = jh+2
                float v0 = (jh     < na) ? x_b[(size_t)e0 * DIN + m] : 0.f;
                float v1 = (jh + 2 < na) ? x_b[(size_t)e1 * DIN + m] : 0.f;
                xbuf[w][m * 4 + jh]     = v0;           // zero-pad => exact 0 contribution
                xbuf[w][m * 4 + jh + 2] = v1;
            }
            // Wave-synchronous LDS handoff: same-wave DS ops execute in order
            // on CDNA; wave_barrier stops the compiler hoisting reads above.
            __builtin_amdgcn_wave_barrier();

            // ---- h1[o=lane] for 4 atoms: 32x64 matvec, silu ----
            float h0 = 0.f, h1 = 0.f, h2 = 0.f, h3 = 0.f;
            #pragma unroll
            for (int m = 0; m < 32; ++m) {
                float  wv = W0s[m * 64 + lane];                 // bank=lane%32: conflict-free
                float4 xv = *(const float4*)&xbuf[w][m * 4];    // uniform addr: broadcast
                h0 += xv.x * wv; h1 += xv.y * wv; h2 += xv.z * wv; h3 += xv.w * wv;
            }
            h0 *= sc0; h1 *= sc0; h2 *= sc0; h3 *= sc0;
            h0 = h0 / (1.f + __expf(-h0));
            h1 = h1 / (1.f + __expf(-h1));
            h2 = h2 / (1.f + __expf(-h2));
            h3 = h3 / (1.f + __expf(-h3));
            *(float4*)&h1buf[w][lane * 4] = make_float4(h0, h1, h2, h3);
            __builtin_amdgcn_wave_barrier();

            // ---- h2[o=lane] for 4 atoms: 64x64 matvec, silu; sum over atoms ----
            float z0 = 0.f, z1 = 0.f, z2 = 0.f, z3 = 0.f;
            #pragma unroll
            for (int m = 0; m < 64; ++m) {
                float  wv = W1s[m * 64 + lane];
                float4 hv = *(const float4*)&h1buf[w][m * 4];
                z0 += hv.x * wv; z1 += hv.y * wv; z2 += hv.z * wv; z3 += hv.w * wv;
            }
            z0 *= sc1; z1 *= sc1; z2 *= sc1; z3 *= sc1;
            z0 = z0 / (1.f + __expf(-z0));
            z1 = z1 / (1.f + __expf(-z1));
            z2 = z2 / (1.f + __expf(-z2));
            z3 = z3 / (1.f + __expf(-z3));
            hsbuf[w][lane] = z0 + z1 + z2 + z3;   // y is linear in h2: sum atoms first
            __builtin_amdgcn_wave_barrier();

            // ---- y accumulate: out[lane], out[lane+64] ----
            #pragma unroll
            for (int m = 0; m < 64; m += 4) {
                float4 hv = *(const float4*)&hsbuf[w][m];
                accA += hv.x * Wos[(m + 0) * 128 + lane];
                accB += hv.x * Wos[(m + 0) * 128 + 64 + lane];
                accA += hv.y * Wos[(m + 1) * 128 + lane];
                accB += hv.y * Wos[(m + 1) * 128 + 64 + lane];
                accA += hv.z * Wos[(m + 2) * 128 + lane];
                accB += hv.z * Wos[(m + 2) * 128 + 64 + lane];
                accA += hv.w * Wos[(m + 3) * 128 + lane];
                accB += hv.w * Wos[(m + 3) * 128 + 64 + lane];
            }
        }
    }

    // ---- cross-wave reduction, single write (block owns this slice) ----
    red[w * 128 + lane]      = accA;
    red[w * 128 + 64 + lane] = accB;
    __syncthreads();
    if (tid < 128) {
        float s = red[tid] + red[128 + tid] + red[256 + tid] + red[384 + tid];
        out[(size_t)b * (NCLS * 128) + c * 128 + tid] = s * 0.125f;  // 1/sqrt(HID)
    }
}

extern "C" void kernel_launch(void* const* d_in, const int* in_sizes, int n_in,
                              void* d_out, int out_size, void* d_ws, size_t ws_size,
                              hipStream_t stream) {
    const float* x  = (const float*)d_in[0];
    const float* W0 = (const float*)d_in[1];   // W0_0
    const float* W1 = (const float*)d_in[5];   // W1_0
    const float* Wo = (const float*)d_in[9];   // Wout
    const int*   mp = (const int*)  d_in[10];  // mlp_mapping
    float* outp = (float*)d_out;

    dim3 grid(NCLS, NB);
    eqmlp_fused<<<grid, 256, 0, stream>>>(x, W0, W1, Wo, mp, outp);
}

// Round 3
// 98.873 us; speedup vs baseline: 1.0649x; 1.0649x over previous
//
#include <hip/hip_runtime.h>

// TiledEquivariantMLP — live-path-only implementation, v2.
// Dead-code analysis of the reference: only the l=0 (scalar) channel affects
// the output. Per atom: h1=silu(x0@W0_0[:, :64]/sqrt(32)); h2=silu(h1@W1_0[:, :64]/8);
// y=h2@Wout/8; summed per (batch, class).  (Gates y0[:,64:256] only multiply
// l>0 irreps, which are dead because the final output reads only b[0].)
//
// v2: Wout matvec hoisted out of the atom loop (y is linear in h2 -> sum h2
// over atoms in a register first, one 64x128 matvec per block at the end,
// reading Wout directly from L2 -- no LDS staging for it).
//
// Grid: (10 classes, 32 batches). Each block owns out[b, c*128:(c+1)*128]
// exclusively -> no atomics, no output pre-zero, no workspace.

#define NCLS  10
#define NB    32
#define NATOM 512
#define DIN   272

__global__ __launch_bounds__(256) void eqmlp_fused(
    const float* __restrict__ x,       // (32, 512, 272)
    const float* __restrict__ W0,      // (10, 32, 256)  use cols [0,64)
    const float* __restrict__ W1,      // (10, 64, 256)  use cols [0,64)
    const float* __restrict__ Wo,      // (10, 64, 128)
    const int*   __restrict__ mapping, // (32, 512) values 0..10
    float*       __restrict__ out)     // (32, 1280)
{
    const int c    = blockIdx.x;
    const int b    = blockIdx.y;
    const int tid  = threadIdx.x;
    const int w    = tid >> 6;   // wave 0..3
    const int lane = tid & 63;

    __shared__ __align__(16) float W0s[32 * 64];     //  8 KB  [m][o]
    __shared__ __align__(16) float W1s[64 * 64];     // 16 KB  [m][o]
    __shared__ __align__(16) float xbuf [4][32 * 4]; // per-wave, m-major x4 atoms
    __shared__ __align__(16) float h1buf[4][64 * 4]; // per-wave
    __shared__ __align__(16) float hsum[4][64];      // per-wave atom-summed h2
    __shared__ __align__(16) float fin[2][128];

    // ---- mapping loads first (independent of weight staging) ----
    const int* map_b = mapping + b * NATOM;
    const int  mv0 = map_b[w * 128 + lane];
    const int  mv1 = map_b[w * 128 + 64 + lane];

    // ---- stage live weight slices into LDS (coalesced float4) ----
    {
        const float4* g0 = (const float4*)(W0 + (size_t)c * 32 * 256);
        float4* s0 = (float4*)W0s;
        for (int i = tid; i < 32 * 64 / 4; i += 256)       // o-slice [0,64)
            s0[i] = g0[(i >> 4) * 64 + (i & 15)];
        const float4* g1 = (const float4*)(W1 + (size_t)c * 64 * 256);
        float4* s1 = (float4*)W1s;
        for (int i = tid; i < 64 * 64 / 4; i += 256)
            s1[i] = g1[(i >> 4) * 64 + (i & 15)];
    }
    __syncthreads();

    float zacc = 0.f;   // sum over this wave's atoms of silu(h2)[lane]

    const float* x_b = x + (size_t)b * NATOM * DIN;
    const float  sc0 = 0.17677669529663689f;  // 1/sqrt(32)
    const float  sc1 = 0.125f;                // 1/sqrt(64)

    for (int chunk = 0; chunk < 2; ++chunk) {
        const int base = w * 128 + chunk * 64;          // this wave's 64 atoms
        unsigned long long mask = __ballot((chunk ? mv1 : mv0) == c);

        while (mask) {
            // ---- pop up to 4 matched atom indices (wave-uniform scalars) ----
            int a0 = 0, a1 = 0, a2 = 0, a3 = 0, na = 0;
            {             int p = __builtin_ctzll(mask); mask &= mask - 1; a0 = base + p; na = 1; }
            if (mask)   { int p = __builtin_ctzll(mask); mask &= mask - 1; a1 = base + p; na = 2; }
            if (mask)   { int p = __builtin_ctzll(mask); mask &= mask - 1; a2 = base + p; na = 3; }
            if (mask)   { int p = __builtin_ctzll(mask); mask &= mask - 1; a3 = base + p; na = 4; }

            // ---- load x0 (first 32 feats) for up to 4 atoms, m-major in LDS ----
            {
                const int m  = lane & 31;
                const int jh = lane >> 5;               // 0 or 1
                const int e0 = jh ? a1 : a0;            // j = jh
                const int e1 = jh ? a3 : a2;            // j = jh+2
                float v0 = (jh     < na) ? x_b[(size_t)e0 * DIN + m] : 0.f;
                float v1 = (jh + 2 < na) ? x_b[(size_t)e1 * DIN + m] : 0.f;
                xbuf[w][m * 4 + jh]     = v0;           // zero-pad => exact 0 contribution
                xbuf[w][m * 4 + jh + 2] = v1;
            }
            // Wave-synchronous LDS handoff: same-wave DS ops execute in order
            // on CDNA; wave_barrier stops the compiler from reordering.
            __builtin_amdgcn_wave_barrier();

            // ---- h1[o=lane] for 4 atoms: 32x64 matvec, silu ----
            float h0 = 0.f, h1 = 0.f, h2 = 0.f, h3 = 0.f;
            #pragma unroll
            for (int m = 0; m < 32; ++m) {
                float  wv = W0s[m * 64 + lane];                 // bank=lane%32: conflict-free
                float4 xv = *(const float4*)&xbuf[w][m * 4];    // uniform addr: broadcast
                h0 += xv.x * wv; h1 += xv.y * wv; h2 += xv.z * wv; h3 += xv.w * wv;
            }
            h0 *= sc0; h1 *= sc0; h2 *= sc0; h3 *= sc0;
            h0 = h0 / (1.f + __expf(-h0));
            h1 = h1 / (1.f + __expf(-h1));
            h2 = h2 / (1.f + __expf(-h2));
            h3 = h3 / (1.f + __expf(-h3));
            *(float4*)&h1buf[w][lane * 4] = make_float4(h0, h1, h2, h3);
            __builtin_amdgcn_wave_barrier();

            // ---- h2[o=lane] for 4 atoms: 64x64 matvec, silu; accumulate ----
            float z0 = 0.f, z1 = 0.f, z2 = 0.f, z3 = 0.f;
            #pragma unroll
            for (int m = 0; m < 64; ++m) {
                float  wv = W1s[m * 64 + lane];
                float4 hv = *(const float4*)&h1buf[w][m * 4];
                z0 += hv.x * wv; z1 += hv.y * wv; z2 += hv.z * wv; z3 += hv.w * wv;
            }
            z0 *= sc1; z1 *= sc1; z2 *= sc1; z3 *= sc1;
            zacc += z0 / (1.f + __expf(-z0));
            zacc += z1 / (1.f + __expf(-z1));
            zacc += z2 / (1.f + __expf(-z2));
            zacc += z3 / (1.f + __expf(-z3));
            // keep next iteration's xbuf write below this iteration's reads
            __builtin_amdgcn_wave_barrier();
        }
    }

    // ---- cross-wave h2-sum reduction ----
    hsum[w][lane] = zacc;
    __syncthreads();
    if (tid < 64)
        hsum[0][tid] += hsum[1][tid] + hsum[2][tid] + hsum[3][tid];
    __syncthreads();

    // ---- final 64x128 matvec, once per block, Wout direct from L2 ----
    // 256 threads = 128 cols x 2 m-halves; coalesced global reads.
    const int col  = tid & 127;
    const int half = tid >> 7;
    const float* Wo_c = Wo + (size_t)c * 64 * 128 + col;
    float acc = 0.f;
    #pragma unroll
    for (int mm = 0; mm < 32; mm += 4) {
        const int m = half * 32 + mm;
        float4 hv = *(const float4*)&hsum[0][m];   // uniform addr: broadcast
        acc += hv.x * Wo_c[(size_t)(m + 0) * 128];
        acc += hv.y * Wo_c[(size_t)(m + 1) * 128];
        acc += hv.z * Wo_c[(size_t)(m + 2) * 128];
        acc += hv.w * Wo_c[(size_t)(m + 3) * 128];
    }
    fin[half][col] = acc;
    __syncthreads();
    if (tid < 128)
        out[(size_t)b * (NCLS * 128) + c * 128 + tid]
            = (fin[0][tid] + fin[1][tid]) * 0.125f;   // 1/sqrt(HID)
}

extern "C" void kernel_launch(void* const* d_in, const int* in_sizes, int n_in,
                              void* d_out, int out_size, void* d_ws, size_t ws_size,
                              hipStream_t stream) {
    const float* x  = (const float*)d_in[0];
    const float* W0 = (const float*)d_in[1];   // W0_0
    const float* W1 = (const float*)d_in[5];   // W1_0
    const float* Wo = (const float*)d_in[9];   // Wout
    const int*   mp = (const int*)  d_in[10];  // mlp_mapping
    float* outp = (float*)d_out;

    dim3 grid(NCLS, NB);
    eqmlp_fused<<<grid, 256, 0, stream>>>(x, W0, W1, Wo, mp, outp);
}

// Round 5
// 93.262 us; speedup vs baseline: 1.1290x; 1.0602x over previous
//
#include <hip/hip_runtime.h>

// TiledEquivariantMLP — live-path-only implementation, v3.
// Only the l=0 (scalar) channel affects the output (gates y0[:,64:256] feed
// only l>0 irreps, which are dead). Per atom:
//   h1 = silu(x[:, :32] @ W0_0[:, :64] / sqrt(32))
//   h2 = silu(h1 @ W1_0[:, :64] / 8)
//   out[b, c] = (sum_{atoms in class c} h2) @ Wout[c] / 8     (linear => hoist)
//
// v3 vs v2:
//  - block-level compaction: all matched atom indices into an LDS list,
//    groups of 4 assigned round-robin to waves (balances Binomial skew).
//  - software-pipelined x gather: next group's global loads issued before
//    the current group's matvecs (hides ~600cyc gather latency).
//
// Grid: (10 classes, 32 batches). Each block owns out[b, c*128:(c+1)*128]
// exclusively -> no atomics, no output pre-zero, no workspace.

#define NCLS  10
#define NB    32
#define NATOM 512
#define DIN   272

__global__ __launch_bounds__(256) void eqmlp_fused(
    const float* __restrict__ x,       // (32, 512, 272)
    const float* __restrict__ W0,      // (10, 32, 256)  use cols [0,64)
    const float* __restrict__ W1,      // (10, 64, 256)  use cols [0,64)
    const float* __restrict__ Wo,      // (10, 64, 128)
    const int*   __restrict__ mapping, // (32, 512) values 0..10
    float*       __restrict__ out)     // (32, 1280)
{
    const int c    = blockIdx.x;
    const int b    = blockIdx.y;
    const int tid  = threadIdx.x;
    const int w    = tid >> 6;   // wave 0..3
    const int lane = tid & 63;

    __shared__ __align__(16) float W0s[32 * 64];     //  8 KB  [m][o]
    __shared__ __align__(16) float W1s[64 * 64];     // 16 KB  [m][o]
    __shared__ __align__(16) float xbuf [4][32 * 4]; // per-wave, m-major x4 atoms
    __shared__ __align__(16) float h1buf[4][64 * 4]; // per-wave
    __shared__ __align__(16) float hsum[4][64];      // per-wave atom-summed h2
    __shared__ __align__(16) float fin[2][128];
    __shared__ int alist[NATOM];                     // compacted matched atoms
    __shared__ int scnt[8], soff[8], stotal;

    // ---- mapping loads (independent of everything else) ----
    const int* map_b = mapping + b * NATOM;
    const int  mv0 = map_b[w * 128 + lane];
    const int  mv1 = map_b[w * 128 + 64 + lane];

    // ---- stage live weight slices into LDS (issued early; the compaction
    //      __syncthreads below also serve as the staging barrier) ----
    {
        const float4* g0 = (const float4*)(W0 + (size_t)c * 32 * 256);
        float4* s0 = (float4*)W0s;
        for (int i = tid; i < 32 * 64 / 4; i += 256)       // o-slice [0,64)
            s0[i] = g0[(i >> 4) * 64 + (i & 15)];
        const float4* g1 = (const float4*)(W1 + (size_t)c * 64 * 256);
        float4* s1 = (float4*)W1s;
        for (int i = tid; i < 64 * 64 / 4; i += 256)
            s1[i] = g1[(i >> 4) * 64 + (i & 15)];
    }

    // ---- block-level compaction of matched atom indices ----
    const unsigned long long bal0 = __ballot(mv0 == c);
    const unsigned long long bal1 = __ballot(mv1 == c);
    if (lane == 0) {
        scnt[w * 2]     = (int)__popcll(bal0);
        scnt[w * 2 + 1] = (int)__popcll(bal1);
    }
    __syncthreads();
    if (tid == 0) {
        int s = 0;
        #pragma unroll
        for (int i = 0; i < 8; ++i) { soff[i] = s; s += scnt[i]; }
        stotal = s;
    }
    __syncthreads();
    {
        const unsigned long long lt = (1ull << lane) - 1ull;  // lane<64 safe
        if (mv0 == c) alist[soff[w * 2]     + (int)__popcll(bal0 & lt)] = w * 128 + lane;
        if (mv1 == c) alist[soff[w * 2 + 1] + (int)__popcll(bal1 & lt)] = w * 128 + 64 + lane;
    }
    __syncthreads();
    const int total   = stotal;
    const int ngroups = (total + 3) >> 2;

    // ---- group loop: round-robin groups across waves, pipelined gather ----
    float zacc = 0.f;   // sum over atoms of silu(h2)[lane]
    const float* x_b = x + (size_t)b * NATOM * DIN;
    const float  sc0 = 0.17677669529663689f;  // 1/sqrt(32)
    const float  sc1 = 0.125f;                // 1/sqrt(64)
    const int    m   = lane & 31;
    const int    jh  = lane >> 5;             // 0 or 1

    float v0 = 0.f, v1 = 0.f;
    if (w < ngroups) {
        int s0 = w * 4 + jh, s1 = s0 + 2;
        int e0 = (s0 < total) ? alist[s0] : -1;
        int e1 = (s1 < total) ? alist[s1] : -1;
        v0 = (e0 >= 0) ? x_b[(size_t)e0 * DIN + m] : 0.f;
        v1 = (e1 >= 0) ? x_b[(size_t)e1 * DIN + m] : 0.f;
    }

    for (int g = w; g < ngroups; g += 4) {
        // current group's x -> LDS (m-major); zero-pad => exact 0 contribution
        xbuf[w][m * 4 + jh]     = v0;
        xbuf[w][m * 4 + jh + 2] = v1;

        // issue NEXT group's gather now; latency hides under the matvecs
        float nv0 = 0.f, nv1 = 0.f;
        if (g + 4 < ngroups) {
            int s0 = (g + 4) * 4 + jh, s1 = s0 + 2;
            int e0 = (s0 < total) ? alist[s0] : -1;
            int e1 = (s1 < total) ? alist[s1] : -1;
            nv0 = (e0 >= 0) ? x_b[(size_t)e0 * DIN + m] : 0.f;
            nv1 = (e1 >= 0) ? x_b[(size_t)e1 * DIN + m] : 0.f;
        }
        // Wave-synchronous LDS handoff: same-wave DS ops execute in order on
        // CDNA; wave_barrier stops the compiler from reordering across it.
        __builtin_amdgcn_wave_barrier();

        // ---- h1[o=lane] for 4 atoms: 32x64 matvec, silu ----
        float h0 = 0.f, h1 = 0.f, h2 = 0.f, h3 = 0.f;
        #pragma unroll
        for (int mm = 0; mm < 32; ++mm) {
            float  wv = W0s[mm * 64 + lane];                 // bank=lane%32: conflict-free
            float4 xv = *(const float4*)&xbuf[w][mm * 4];    // uniform addr: broadcast
            h0 += xv.x * wv; h1 += xv.y * wv; h2 += xv.z * wv; h3 += xv.w * wv;
        }
        h0 *= sc0; h1 *= sc0; h2 *= sc0; h3 *= sc0;
        h0 = h0 / (1.f + __expf(-h0));
        h1 = h1 / (1.f + __expf(-h1));
        h2 = h2 / (1.f + __expf(-h2));
        h3 = h3 / (1.f + __expf(-h3));
        *(float4*)&h1buf[w][lane * 4] = make_float4(h0, h1, h2, h3);
        __builtin_amdgcn_wave_barrier();

        // ---- h2[o=lane] for 4 atoms: 64x64 matvec, silu; accumulate ----
        float z0 = 0.f, z1 = 0.f, z2 = 0.f, z3 = 0.f;
        #pragma unroll
        for (int mm = 0; mm < 64; ++mm) {
            float  wv = W1s[mm * 64 + lane];
            float4 hv = *(const float4*)&h1buf[w][mm * 4];
            z0 += hv.x * wv; z1 += hv.y * wv; z2 += hv.z * wv; z3 += hv.w * wv;
        }
        z0 *= sc1; z1 *= sc1; z2 *= sc1; z3 *= sc1;
        zacc += z0 / (1.f + __expf(-z0));
        zacc += z1 / (1.f + __expf(-z1));
        zacc += z2 / (1.f + __expf(-z2));
        zacc += z3 / (1.f + __expf(-z3));
        // keep next iteration's xbuf write below this iteration's LDS reads
        __builtin_amdgcn_wave_barrier();

        v0 = nv0; v1 = nv1;
    }

    // ---- cross-wave h2-sum reduction ----
    hsum[w][lane] = zacc;
    __syncthreads();
    if (tid < 64)
        hsum[0][tid] += hsum[1][tid] + hsum[2][tid] + hsum[3][tid];
    __syncthreads();

    // ---- final 64x128 matvec, once per block, Wout direct from L2 ----
    const int col  = tid & 127;
    const int half = tid >> 7;
    const float* Wo_c = Wo + (size_t)c * 64 * 128 + col;
    float acc = 0.f;
    #pragma unroll
    for (int mm = 0; mm < 32; mm += 4) {
        const int mr = half * 32 + mm;
        float4 hv = *(const float4*)&hsum[0][mr];   // uniform addr: broadcast
        acc += hv.x * Wo_c[(size_t)(mr + 0) * 128];
        acc += hv.y * Wo_c[(size_t)(mr + 1) * 128];
        acc += hv.z * Wo_c[(size_t)(mr + 2) * 128];
        acc += hv.w * Wo_c[(size_t)(mr + 3) * 128];
    }
    fin[half][col] = acc;
    __syncthreads();
    if (tid < 128)
        out[(size_t)b * (NCLS * 128) + c * 128 + tid]
            = (fin[0][tid] + fin[1][tid]) * 0.125f;   // 1/sqrt(HID)
}

extern "C" void kernel_launch(void* const* d_in, const int* in_sizes, int n_in,
                              void* d_out, int out_size, void* d_ws, size_t ws_size,
                              hipStream_t stream) {
    const float* x  = (const float*)d_in[0];
    const float* W0 = (const float*)d_in[1];   // W0_0
    const float* W1 = (const float*)d_in[5];   // W1_0
    const float* Wo = (const float*)d_in[9];   // Wout
    const int*   mp = (const int*)  d_in[10];  // mlp_mapping
    float* outp = (float*)d_out;

    dim3 grid(NCLS, NB);
    eqmlp_fused<<<grid, 256, 0, stream>>>(x, W0, W1, Wo, mp, outp);
}